// Round 3
// baseline (299.720 us; speedup 1.0000x reference)
//
#include <hip/hip_runtime.h>
#include <hip/hip_fp16.h>

// SiameseEdgeConvNet: 2-layer EdgeConv (max aggr) on two graphs, shared weights.
// N=50000, E=1.6e6, dims 32 -> 64 -> 64.
//
// Algebra: msg = relu([xi, xj-xi] @ W + b) = relu(xi@A + xj@B + b),
//   A=W_lo-W_hi, B=W_hi.  u = x@A + b, v = x@B per node; ReLU monotone =>
//   out[d] = relu(u[d] + max_{e: dst=d} v[src_e]);  empty segment -> 0
//   (matches jax isfinite->0 fixup).  PReLU input >= 0 -> identity -> skipped.
//
// R15 (on top of R14's bucket-bin + LDS counting sort + register pk_max):
//   * agg FETCH was 114 MB vs ~38 MB compulsory: random gathers from a
//     6.4 MB vk table thrash the 4 MB per-XCD L2 (~75 MB refetch). Fix:
//     TWO half-row passes (64 B each: uint2 slots 0-7 then 8-15). Each
//     pass's line footprint is 3.2 MB/graph -> L2-resident. Gather/pkmax
//     instruction counts unchanged (8-lane groups, dwordx2/lane).
//   * lists padded to multiples of 8 with sentinel src=N (vk row N = -inf,
//     initialized once in prep_w, never written by gemm) -> no remainder
//     loop, less divergence.
//   * bin WRITE was 72 MB vs 12.8 MB payload: 1563 buckets -> 2.6-record
//     (10 B) runs dirty whole lines; 16 KB LDS hist capped occupancy at 23%.
//     TILE 32 -> 128 (NB=391): runs ~10.5 rec = 42 B, hist 4 KB.
//     agg counting sort absorbs it: lrec[128][96] = 24 KB LDS, 128 counters
//     (less atomic contention than 32). CAP=5120 = mean 4096 + 16 sigma.

constexpr int HID   = 64;
constexpr int TILE  = 128;          // nodes per bucket (dst >> 7)
constexpr int TSH   = 7;            // log2(TILE)
constexpr int CAP   = 5120;         // records per bucket (mean 4096, +16s)
constexpr int MAXNB = 512;          // max buckets (N <= 65536)
constexpr int EPT   = 16;           // edges per thread in bin_kernel
constexpr int CAPN  = 96;           // per-node capacity (mean deg 32, max ~70)

typedef _Float16 half8 __attribute__((ext_vector_type(8)));
typedef float    f32x4 __attribute__((ext_vector_type(4)));

__device__ __forceinline__ unsigned int pkmax(unsigned int a, unsigned int b) {
    unsigned int d;
    asm("v_pk_max_f16 %0, %1, %2" : "=v"(d) : "v"(a), "v"(b));
    return d;
}
__device__ __forceinline__ unsigned int f2hbits(float f) {
    const __half h = __float2half_rn(f);
    return (unsigned int)*reinterpret_cast<const unsigned short*>(&h);
}
__device__ __forceinline__ float h2f(unsigned int b16) {
    const unsigned short b = (unsigned short)b16;
    __half h;
    *reinterpret_cast<unsigned short*>(&h) = b;
    return __half2float(h);
}

struct G {                    // one graph's pointer set
    const float* x;           // [N,32] layer-1 input
    const int*   src;         // [E]
    const int*   dst;         // [E]
    int* bcnt;                // [NB]       bucket fill counters
    unsigned int* bin;        // [NB*CAP]   packed records (src<<7 | dst&127)
    float*          u;        // [N,64] fp32
    unsigned short* vk;       // [(N+1),64] fp16, permuted: uint2 slot m of a
                              //   row holds channels {m, m+16, m+32, m+48};
                              //   row N = -inf sentinel (set once in prep_w)
    float*          out;      // [N,64] — h after layer 1, final after layer 2
};

// ---- weight prep + vk sentinel row init ----
__global__ __launch_bounds__(256) void prep_w_kernel(
    const float* __restrict__ W1, const float* __restrict__ W2,
    _Float16* __restrict__ Wc1, _Float16* __restrict__ Wc2,
    unsigned short* __restrict__ vkS0, unsigned short* __restrict__ vkS1, int N)
{
    const int i = blockIdx.x * 256 + threadIdx.x;
    if (i < 32 * 64) {
        const int k = i >> 6, c = i & 63;
        const float lo = W1[k * 64 + c], hi = W1[(32 + k) * 64 + c];
        Wc1[k * 128 + c]      = (_Float16)(lo - hi);
        Wc1[k * 128 + 64 + c] = (_Float16)hi;
    }
    const int j = i - 32 * 64;
    if (j >= 0 && j < 64 * 64) {
        const int k = j >> 6, c = j & 63;
        const float lo = W2[k * 64 + c], hi = W2[(64 + k) * 64 + c];
        Wc2[k * 128 + c]      = (_Float16)(lo - hi);
        Wc2[k * 128 + 64 + c] = (_Float16)hi;
    }
    const int q = i - (32 * 64 + 64 * 64);
    if (q >= 0 && q < 2 * HID) {                 // sentinel rows = -inf fp16
        if (q < HID) vkS0[(size_t)N * HID + q]       = 0xFC00u;
        else         vkS1[(size_t)N * HID + (q-HID)] = 0xFC00u;
    }
}

// ---- bin: block-reserved capacity scatter of packed records ----
__global__ __launch_bounds__(256) void bin_kernel(G g0, G g1, int E, int NB) {
    const G g = blockIdx.y ? g1 : g0;
    __shared__ int lh[MAXNB];   // local hist, then local write offset
    __shared__ int lb[MAXNB];   // reserved base per bucket
    for (int i = threadIdx.x; i < NB; i += 256) lh[i] = 0;
    __syncthreads();

    const int base = blockIdx.x * 256 * EPT;
    unsigned int rec[EPT];
    int bb[EPT];
    #pragma unroll
    for (int k = 0; k < EPT; ++k) {
        const int i = base + k * 256 + threadIdx.x;   // coalesced stream
        if (i < E) {
            const int d = g.dst[i];
            const int s = g.src[i];
            rec[k] = ((unsigned int)s << TSH) | (unsigned int)(d & (TILE - 1));
            bb[k]  = d >> TSH;
            atomicAdd(&lh[bb[k]], 1);
        } else bb[k] = -1;
    }
    __syncthreads();
    for (int t = threadIdx.x; t < NB; t += 256) {
        const int c = lh[t];
        lb[t] = c ? atomicAdd(&g.bcnt[t], c) : 0;   // global range reservation
        lh[t] = 0;
    }
    __syncthreads();
    #pragma unroll
    for (int k = 0; k < EPT; ++k) {
        if (bb[k] >= 0) {
            const int off = atomicAdd(&lh[bb[k]], 1);
            const int pos = lb[bb[k]] + off;
            if (pos < CAP)                            // 16-sigma guard
                g.bin[(size_t)bb[k] * CAP + pos] = rec[k];
        }
    }
}

// ---- MFMA node GEMM: [u|v](N x 128) = in(N x K) @ Wc(K x 128); u += bias ----
// v emitted as raw fp16, channel-permuted: uint2 slot m of a row holds
// channels {m, m+16, m+32, m+48} (position 4m+t = channel 16t+m).
template<int K>
__global__ __launch_bounds__(256) void gemm_mfma_kernel(
    G g0, G g1, const _Float16* __restrict__ Wc,
    const float* __restrict__ bias, int N)
{
    const G g = blockIdx.y ? g1 : g0;
    constexpr int KH = K / 32;                 // k-halves (1 or 2)
    const int lane = threadIdx.x & 63;
    const int m    = lane & 15;                // A row / D col-lane
    const int quad = lane >> 4;
    const int wid  = (blockIdx.x * 256 + threadIdx.x) >> 6;
    const int nW   = (gridDim.x * 256) >> 6;

    // B-frags: B[k=32h+quad*8+j][n=16t+m]
    half8 bf[8][KH];
    #pragma unroll
    for (int t = 0; t < 8; ++t)
        #pragma unroll
        for (int h = 0; h < KH; ++h)
            #pragma unroll
            for (int j = 0; j < 8; ++j)
                bf[t][h][j] = Wc[(h * 32 + quad * 8 + j) * 128 + t * 16 + m];

    float bv[4];
    #pragma unroll
    for (int t = 0; t < 4; ++t) bv[t] = bias[t * 16 + m];

    const float* __restrict__ inp = (K == 32) ? g.x : g.out;
    const int tiles = (N + 15) / 16;

    for (int tile = wid; tile < tiles; tile += nW) {
        const int nbase = tile * 16;
        const int nodeA = min(nbase + m, N - 1);
        const float4* rp = (const float4*)(inp + (size_t)nodeA * K);

        half8 a[KH];
        #pragma unroll
        for (int h = 0; h < KH; ++h) {
            const float4 f0 = rp[h * 8 + quad * 2];
            const float4 f1 = rp[h * 8 + quad * 2 + 1];
            a[h][0] = (_Float16)f0.x; a[h][1] = (_Float16)f0.y;
            a[h][2] = (_Float16)f0.z; a[h][3] = (_Float16)f0.w;
            a[h][4] = (_Float16)f1.x; a[h][5] = (_Float16)f1.y;
            a[h][6] = (_Float16)f1.z; a[h][7] = (_Float16)f1.w;
        }

        f32x4 acc[8];
        #pragma unroll
        for (int t = 0; t < 8; ++t) {
            acc[t] = (f32x4){0.f, 0.f, 0.f, 0.f};
            #pragma unroll
            for (int h = 0; h < KH; ++h)
                acc[t] = __builtin_amdgcn_mfma_f32_16x16x32_f16(
                    a[h], bf[t][h], acc[t], 0, 0, 0);
        }

        // D[m=quad*4+r][n=lane&15]
        #pragma unroll
        for (int r = 0; r < 4; ++r) {
            const int node = nbase + quad * 4 + r;
            if (node < N) {
                float* urow = g.u + (size_t)node * HID;
                #pragma unroll
                for (int t = 0; t < 4; ++t)
                    urow[t * 16 + m] = acc[t][r] + bv[t];
                const unsigned int e0 = f2hbits(acc[4][r]);   // channel m
                const unsigned int e1 = f2hbits(acc[5][r]);   // channel m+16
                const unsigned int e2 = f2hbits(acc[6][r]);   // channel m+32
                const unsigned int e3 = f2hbits(acc[7][r]);   // channel m+48
                uint2 pack;
                pack.x = (e1 << 16) | e0;
                pack.y = (e3 << 16) | e2;
                ((uint2*)(g.vk + (size_t)node * HID))[m] = pack;
            }
        }
    }
}

// ---- aggregate: one block per 128-node bucket ----
// Phase A: coalesced record read + LDS counting sort into per-node lists,
//   padded to multiples of 8 with sentinel src=N (-inf row).
// Phase B: 8-lane group per node (4 nodes per group, sequential), running max
//   in registers via v_pk_max_f16. TWO half-row passes (uint2 slots 0-7 then
//   8-15): each pass's gather line-footprint is 3.2 MB/graph -> L2-resident
//   (vs 6.4 MB full-row thrashing the 4 MB/XCD L2; FETCH was 114 MB).
__global__ __launch_bounds__(256) void agg_kernel(G g0, G g1, int N, int NB, int two) {
    int b, gi;
    if (two) {                       // XCD partition: bid%8 -> XCD (heuristic)
        const int bid = blockIdx.x;
        const int xcd = bid & 7;
        gi = xcd >> 2;               // XCD 0-3: graph 0, XCD 4-7: graph 1
        b  = (bid >> 3) * 4 + (xcd & 3);
    } else { gi = 0; b = blockIdx.x; }
    if (b >= NB) return;
    const G g = gi ? g1 : g0;

    __shared__ int lcnt[TILE];
    __shared__ unsigned short lrec[TILE][CAPN];   // 24 KB, rows 16B-aligned
    for (int i = threadIdx.x; i < TILE; i += 256) lcnt[i] = 0;
    __syncthreads();

    const int cnt = min(g.bcnt[b], CAP);
    const unsigned int* __restrict__ bp = g.bin + (size_t)b * CAP;
    for (int i = threadIdx.x; i < cnt; i += 256) {
        const unsigned int rec = bp[i];
        const int d = rec & (TILE - 1);
        const int p = atomicAdd(&lcnt[d], 1);
        if (p < CAPN) lrec[d][p] = (unsigned short)(rec >> TSH);
    }
    __syncthreads();
    for (int t = threadIdx.x; t < TILE; t += 256) {   // pad to x8 w/ sentinel
        const int c  = min(lcnt[t], CAPN);
        const int cp = (c + 7) & ~7;
        for (int p = c; p < cp; ++p) lrec[t][p] = (unsigned short)N;
        lcnt[t] = cp;
    }
    __syncthreads();

    const int grp = threadIdx.x >> 3;        // 32 groups of 8 lanes
    const int sub = threadIdx.x & 7;
    const uint2* __restrict__ vk2 = (const uint2*)g.vk;

    unsigned int mA[4][2], mB[4][2];
    int cp4[4];

    #pragma unroll
    for (int i = 0; i < 4; ++i) {            // pass A: slots sub (low 64 B)
        const int nl = grp + 32 * i;
        cp4[i] = lcnt[nl];
        unsigned int m0 = 0xFC00FC00u, m1 = 0xFC00FC00u;
        for (int j = 0; j < cp4[i]; j += 8) {
            const uint4 rq = *(const uint4*)(&lrec[nl][j]);   // 8 recs, bcast
            unsigned int s[8];
            s[0] = rq.x & 0xFFFFu; s[1] = rq.x >> 16;
            s[2] = rq.y & 0xFFFFu; s[3] = rq.y >> 16;
            s[4] = rq.z & 0xFFFFu; s[5] = rq.z >> 16;
            s[6] = rq.w & 0xFFFFu; s[7] = rq.w >> 16;
            uint2 a[8];
            #pragma unroll
            for (int k = 0; k < 8; ++k) a[k] = vk2[(size_t)s[k] * 16 + sub];
            #pragma unroll
            for (int k = 0; k < 8; ++k) {
                m0 = pkmax(m0, a[k].x);
                m1 = pkmax(m1, a[k].y);
            }
        }
        mA[i][0] = m0; mA[i][1] = m1;
    }

    #pragma unroll
    for (int i = 0; i < 4; ++i) {            // pass B: slots sub+8 (high 64 B)
        const int nl = grp + 32 * i;
        unsigned int m0 = 0xFC00FC00u, m1 = 0xFC00FC00u;
        for (int j = 0; j < cp4[i]; j += 8) {
            const uint4 rq = *(const uint4*)(&lrec[nl][j]);
            unsigned int s[8];
            s[0] = rq.x & 0xFFFFu; s[1] = rq.x >> 16;
            s[2] = rq.y & 0xFFFFu; s[3] = rq.y >> 16;
            s[4] = rq.z & 0xFFFFu; s[5] = rq.z >> 16;
            s[6] = rq.w & 0xFFFFu; s[7] = rq.w >> 16;
            uint2 a[8];
            #pragma unroll
            for (int k = 0; k < 8; ++k) a[k] = vk2[(size_t)s[k] * 16 + 8 + sub];
            #pragma unroll
            for (int k = 0; k < 8; ++k) {
                m0 = pkmax(m0, a[k].x);
                m1 = pkmax(m1, a[k].y);
            }
        }
        mB[i][0] = m0; mB[i][1] = m1;
    }

    #pragma unroll
    for (int i = 0; i < 4; ++i) {            // epilogue: 8 channels per lane
        const int nl = grp + 32 * i;
        const int n  = b * TILE + nl;
        if (n >= N) continue;
        const bool has = cp4[i] > 0;
        const float* __restrict__ urow = g.u + (size_t)n * HID;
        float* __restrict__ orow = g.out + (size_t)n * HID;
        #define PUT(C, HW) \
            orow[C] = has ? fmaxf(urow[C] + h2f(HW), 0.f) : 0.f;
        PUT(sub,      mA[i][0] & 0xFFFFu)  PUT(sub + 16, mA[i][0] >> 16)
        PUT(sub + 32, mA[i][1] & 0xFFFFu)  PUT(sub + 48, mA[i][1] >> 16)
        PUT(sub + 8,  mB[i][0] & 0xFFFFu)  PUT(sub + 24, mB[i][0] >> 16)
        PUT(sub + 40, mB[i][1] & 0xFFFFu)  PUT(sub + 56, mB[i][1] >> 16)
        #undef PUT
    }
}

// ---------------- orchestration ----------------

extern "C" void kernel_launch(void* const* d_in, const int* in_sizes, int n_in,
                              void* d_out, int out_size, void* d_ws, size_t ws_size,
                              hipStream_t stream) {
    const float* x1  = (const float*)d_in[0];
    const int*   ei1 = (const int*)d_in[1];   // [2,E]: src row then dst row
    const float* x2  = (const float*)d_in[2];
    const int*   ei2 = (const int*)d_in[3];
    const float* W1  = (const float*)d_in[4];
    const float* b1  = (const float*)d_in[5];
    // d_in[6] = prelu_a: unused (identity on >=0)
    const float* W2  = (const float*)d_in[7];
    const float* b2  = (const float*)d_in[8];

    const int N  = in_sizes[0] / 32;
    const int E  = in_sizes[1] / 2;
    const int NB = (N + TILE - 1) / TILE;     // 391 for N=50000
    float* out = (float*)d_out;

    const size_t rowB = (size_t)N * HID * sizeof(float);            // 12.8 MB
    const size_t vkB  = ((size_t)(N + 1) * HID * 2 + 63) & ~(size_t)63;
    const size_t binB = ((size_t)NB * CAP * sizeof(int) + 63) & ~(size_t)63;
    const size_t nbB  = ((size_t)(NB + 2) * sizeof(int) + 63) & ~(size_t)63;
    const size_t wc1B = ((size_t)32 * 128 * 2 + 63) & ~(size_t)63;
    const size_t wc2B = ((size_t)64 * 128 * 2 + 63) & ~(size_t)63;

    const int bBlk = (E + 256 * EPT - 1) / (256 * EPT);
    const int gBlk = 256;
    const int pBlk = (32 * 64 + 64 * 64 + 2 * HID + 255) / 256;
    const int aggBlk2 = ((NB + 3) / 4) * 8;   // XCD-partitioned 1D grid

    _Float16* wc1 = nullptr;
    _Float16* wc2 = nullptr;

    auto run = [&](G ga, G gb, int ny) {
        // bcnt arrays contiguous across graphs: one memset when ny==2
        hipMemsetAsync(ga.bcnt, 0, (size_t)ny * nbB, stream);
        bin_kernel <<<dim3(bBlk, ny), 256, 0, stream>>>(ga, gb, E, NB);
        gemm_mfma_kernel<32><<<dim3(gBlk, ny), 256, 0, stream>>>(ga, gb, wc1, b1, N);
        if (ny == 2) agg_kernel<<<aggBlk2, 256, 0, stream>>>(ga, gb, N, NB, 1);
        else         agg_kernel<<<NB,      256, 0, stream>>>(ga, ga, N, NB, 0);
        gemm_mfma_kernel<64><<<dim3(gBlk, ny), 256, 0, stream>>>(ga, gb, wc2, b2, N);
        if (ny == 2) agg_kernel<<<aggBlk2, 256, 0, stream>>>(ga, gb, N, NB, 1);
        else         agg_kernel<<<NB,      256, 0, stream>>>(ga, ga, N, NB, 0);
    };

    char* ws = (char*)d_ws;
    const size_t needBoth = 2 * rowB + 2 * vkB + 2 * binB + 2 * nbB + wc1B + wc2B;

    if (ws_size >= needBoth) {
        float* u0 = (float*)ws;                  ws += rowB;
        float* u1 = (float*)ws;                  ws += rowB;
        unsigned int* bin0 = (unsigned int*)ws;  ws += binB;
        unsigned int* bin1 = (unsigned int*)ws;  ws += binB;
        unsigned short* vk0 = (unsigned short*)ws;  ws += vkB;
        unsigned short* vk1 = (unsigned short*)ws;  ws += vkB;
        wc1 = (_Float16*)ws;                     ws += wc1B;
        wc2 = (_Float16*)ws;                     ws += wc2B;
        int* bcnt0 = (int*)ws;                   ws += nbB;
        int* bcnt1 = (int*)ws;                   // contiguous with bcnt0

        G g0{x1, ei1, ei1 + E, bcnt0, bin0, u0, vk0, out};
        G g1{x2, ei2, ei2 + E, bcnt1, bin1, u1, vk1, out + (size_t)N * HID};
        prep_w_kernel<<<pBlk, 256, 0, stream>>>(W1, W2, wc1, wc2, vk0, vk1, N);
        run(g0, g1, 2);
    } else {
        // sequential fallback (~28 MB): one graph's buffers, reused
        float* u = (float*)ws;                   ws += rowB;
        unsigned int* bin = (unsigned int*)ws;   ws += binB;
        unsigned short* vk = (unsigned short*)ws;  ws += vkB;
        wc1 = (_Float16*)ws;                     ws += wc1B;
        wc2 = (_Float16*)ws;                     ws += wc2B;
        int* bcnt = (int*)ws;

        prep_w_kernel<<<pBlk, 256, 0, stream>>>(W1, W2, wc1, wc2, vk, vk, N);
        for (int g = 0; g < 2; ++g) {
            const int* ei = g ? ei2 : ei1;
            G gp{g ? x2 : x1, ei, ei + E, bcnt, bin,
                 u, vk, out + (size_t)g * N * HID};
            run(gp, gp, 1);
        }
    }
}

// Round 4
// 264.261 us; speedup vs baseline: 1.1342x; 1.1342x over previous
//
#include <hip/hip_runtime.h>
#include <hip/hip_fp16.h>

// SiameseEdgeConvNet: 2-layer EdgeConv (max aggr) on two graphs, shared weights.
// N=50000, E=1.6e6, dims 32 -> 64 -> 64.
//
// Algebra: msg = relu([xi, xj-xi] @ W + b) = relu(xi@A + xj@B + b),
//   A=W_lo-W_hi, B=W_hi.  u = x@A + b, v = x@B per node; ReLU monotone =>
//   out[d] = relu(u[d] + max_{e: dst=d} v[src_e]);  empty segment -> 0
//   (matches jax isfinite->0 fixup).  PReLU input >= 0 -> identity -> skipped.
//
// R16 (post-mortem of R15's agg regression 48->77 us):
//   * R15 failure 1: TILE=128 -> only 784 agg blocks = 3/CU -> occupancy 23%.
//   * R15 failure 2: two half-row passes are NOT synchronized across blocks,
//     so the combined gather footprint stayed 6.4 MB AND each row was fetched
//     as two 64 B halves at different times -> FETCH 114 -> 168 MB. Reverted.
//   * agg now: 2 blocks per 128-bucket, each owns a 64-node half (grid 1564
//     = 6.1 blocks/CU, LDS 12.6 KB). Block scans the bucket's 16 KB record
//     stream (L2-shared with sibling) keeping its half; phase B = R14's
//     proven full-row dwordx2 gather per 16-lane group, 8 in flight,
//     sentinel-padded lists (no remainder loop).
//   * bin kept at TILE=128 (runs ~5-10 recs, 4 KB LDS hist) but EPT 16->8:
//     782 blocks/graph = 6.1/CU (was 3). bin was latency-bound (1.8 TB/s,
//     VALU 4%, occ 23%) -> occupancy is the lever, not write amp.
//   * gemm grid 256->512 blocks/graph (was 2 blocks/CU).

constexpr int HID   = 64;
constexpr int TILE  = 128;          // nodes per bin bucket (dst >> 7)
constexpr int TSH   = 7;            // log2(TILE)
constexpr int HTILE = 64;           // nodes per agg block (half bucket)
constexpr int CAP   = 5120;         // records per bucket (mean 4096, +16s)
constexpr int MAXNB = 512;          // max buckets (N <= 65536)
constexpr int EPT   = 8;            // edges per thread in bin_kernel
constexpr int CAPN  = 96;           // per-node capacity (mean deg 32, max ~70)

typedef _Float16 half8 __attribute__((ext_vector_type(8)));
typedef float    f32x4 __attribute__((ext_vector_type(4)));

__device__ __forceinline__ unsigned int pkmax(unsigned int a, unsigned int b) {
    unsigned int d;
    asm("v_pk_max_f16 %0, %1, %2" : "=v"(d) : "v"(a), "v"(b));
    return d;
}
__device__ __forceinline__ unsigned int f2hbits(float f) {
    const __half h = __float2half_rn(f);
    return (unsigned int)*reinterpret_cast<const unsigned short*>(&h);
}
__device__ __forceinline__ float h2f(unsigned int b16) {
    const unsigned short b = (unsigned short)b16;
    __half h;
    *reinterpret_cast<unsigned short*>(&h) = b;
    return __half2float(h);
}

struct G {                    // one graph's pointer set
    const float* x;           // [N,32] layer-1 input
    const int*   src;         // [E]
    const int*   dst;         // [E]
    int* bcnt;                // [NB]       bucket fill counters
    unsigned int* bin;        // [NB*CAP]   packed records (src<<7 | dst&127)
    float*          u;        // [N,64] fp32
    unsigned short* vk;       // [(N+1),64] fp16, permuted: uint2 slot m of a
                              //   row holds channels {m, m+16, m+32, m+48};
                              //   row N = -inf sentinel (set once in prep_w)
    float*          out;      // [N,64] — h after layer 1, final after layer 2
};

// ---- weight prep + vk sentinel row init ----
__global__ __launch_bounds__(256) void prep_w_kernel(
    const float* __restrict__ W1, const float* __restrict__ W2,
    _Float16* __restrict__ Wc1, _Float16* __restrict__ Wc2,
    unsigned short* __restrict__ vkS0, unsigned short* __restrict__ vkS1, int N)
{
    const int i = blockIdx.x * 256 + threadIdx.x;
    if (i < 32 * 64) {
        const int k = i >> 6, c = i & 63;
        const float lo = W1[k * 64 + c], hi = W1[(32 + k) * 64 + c];
        Wc1[k * 128 + c]      = (_Float16)(lo - hi);
        Wc1[k * 128 + 64 + c] = (_Float16)hi;
    }
    const int j = i - 32 * 64;
    if (j >= 0 && j < 64 * 64) {
        const int k = j >> 6, c = j & 63;
        const float lo = W2[k * 64 + c], hi = W2[(64 + k) * 64 + c];
        Wc2[k * 128 + c]      = (_Float16)(lo - hi);
        Wc2[k * 128 + 64 + c] = (_Float16)hi;
    }
    const int q = i - (32 * 64 + 64 * 64);
    if (q >= 0 && q < 2 * HID) {                 // sentinel rows = -inf fp16
        if (q < HID) vkS0[(size_t)N * HID + q]       = 0xFC00u;
        else         vkS1[(size_t)N * HID + (q-HID)] = 0xFC00u;
    }
}

// ---- bin: block-reserved capacity scatter of packed records ----
__global__ __launch_bounds__(256) void bin_kernel(G g0, G g1, int E, int NB) {
    const G g = blockIdx.y ? g1 : g0;
    __shared__ int lh[MAXNB];   // local hist, then local write offset
    __shared__ int lb[MAXNB];   // reserved base per bucket
    for (int i = threadIdx.x; i < NB; i += 256) lh[i] = 0;
    __syncthreads();

    const int base = blockIdx.x * 256 * EPT;
    unsigned int rec[EPT];
    int bb[EPT];
    #pragma unroll
    for (int k = 0; k < EPT; ++k) {
        const int i = base + k * 256 + threadIdx.x;   // coalesced stream
        if (i < E) {
            const int d = g.dst[i];
            const int s = g.src[i];
            rec[k] = ((unsigned int)s << TSH) | (unsigned int)(d & (TILE - 1));
            bb[k]  = d >> TSH;
            atomicAdd(&lh[bb[k]], 1);
        } else bb[k] = -1;
    }
    __syncthreads();
    for (int t = threadIdx.x; t < NB; t += 256) {
        const int c = lh[t];
        lb[t] = c ? atomicAdd(&g.bcnt[t], c) : 0;   // global range reservation
        lh[t] = 0;
    }
    __syncthreads();
    #pragma unroll
    for (int k = 0; k < EPT; ++k) {
        if (bb[k] >= 0) {
            const int off = atomicAdd(&lh[bb[k]], 1);
            const int pos = lb[bb[k]] + off;
            if (pos < CAP)                            // 16-sigma guard
                g.bin[(size_t)bb[k] * CAP + pos] = rec[k];
        }
    }
}

// ---- MFMA node GEMM: [u|v](N x 128) = in(N x K) @ Wc(K x 128); u += bias ----
// v emitted as raw fp16, channel-permuted: uint2 slot m of a row holds
// channels {m, m+16, m+32, m+48} (position 4m+t = channel 16t+m).
template<int K>
__global__ __launch_bounds__(256) void gemm_mfma_kernel(
    G g0, G g1, const _Float16* __restrict__ Wc,
    const float* __restrict__ bias, int N)
{
    const G g = blockIdx.y ? g1 : g0;
    constexpr int KH = K / 32;                 // k-halves (1 or 2)
    const int lane = threadIdx.x & 63;
    const int m    = lane & 15;                // A row / D col-lane
    const int quad = lane >> 4;
    const int wid  = (blockIdx.x * 256 + threadIdx.x) >> 6;
    const int nW   = (gridDim.x * 256) >> 6;

    // B-frags: B[k=32h+quad*8+j][n=16t+m]
    half8 bf[8][KH];
    #pragma unroll
    for (int t = 0; t < 8; ++t)
        #pragma unroll
        for (int h = 0; h < KH; ++h)
            #pragma unroll
            for (int j = 0; j < 8; ++j)
                bf[t][h][j] = Wc[(h * 32 + quad * 8 + j) * 128 + t * 16 + m];

    float bv[4];
    #pragma unroll
    for (int t = 0; t < 4; ++t) bv[t] = bias[t * 16 + m];

    const float* __restrict__ inp = (K == 32) ? g.x : g.out;
    const int tiles = (N + 15) / 16;

    for (int tile = wid; tile < tiles; tile += nW) {
        const int nbase = tile * 16;
        const int nodeA = min(nbase + m, N - 1);
        const float4* rp = (const float4*)(inp + (size_t)nodeA * K);

        half8 a[KH];
        #pragma unroll
        for (int h = 0; h < KH; ++h) {
            const float4 f0 = rp[h * 8 + quad * 2];
            const float4 f1 = rp[h * 8 + quad * 2 + 1];
            a[h][0] = (_Float16)f0.x; a[h][1] = (_Float16)f0.y;
            a[h][2] = (_Float16)f0.z; a[h][3] = (_Float16)f0.w;
            a[h][4] = (_Float16)f1.x; a[h][5] = (_Float16)f1.y;
            a[h][6] = (_Float16)f1.z; a[h][7] = (_Float16)f1.w;
        }

        f32x4 acc[8];
        #pragma unroll
        for (int t = 0; t < 8; ++t) {
            acc[t] = (f32x4){0.f, 0.f, 0.f, 0.f};
            #pragma unroll
            for (int h = 0; h < KH; ++h)
                acc[t] = __builtin_amdgcn_mfma_f32_16x16x32_f16(
                    a[h], bf[t][h], acc[t], 0, 0, 0);
        }

        // D[m=quad*4+r][n=lane&15]
        #pragma unroll
        for (int r = 0; r < 4; ++r) {
            const int node = nbase + quad * 4 + r;
            if (node < N) {
                float* urow = g.u + (size_t)node * HID;
                #pragma unroll
                for (int t = 0; t < 4; ++t)
                    urow[t * 16 + m] = acc[t][r] + bv[t];
                const unsigned int e0 = f2hbits(acc[4][r]);   // channel m
                const unsigned int e1 = f2hbits(acc[5][r]);   // channel m+16
                const unsigned int e2 = f2hbits(acc[6][r]);   // channel m+32
                const unsigned int e3 = f2hbits(acc[7][r]);   // channel m+48
                uint2 pack;
                pack.x = (e1 << 16) | e0;
                pack.y = (e3 << 16) | e2;
                ((uint2*)(g.vk + (size_t)node * HID))[m] = pack;
            }
        }
    }
}

// ---- aggregate: 2 blocks per 128-node bucket, 64 nodes each ----
// Phase A: scan the bucket's record stream (L2-shared with sibling block),
//   counting-sort our half into lrec[64][96]; pad lists to x8 with sentinel
//   src=N (-inf vk row).
// Phase B: 16-lane group per node (4 sequential), running max in registers
//   via v_pk_max_f16; full-row dwordx2 gathers, 8 in flight per lane.
__global__ __launch_bounds__(256) void agg_kernel(G g0, G g1, int N, int NB, int two) {
    int idx, gi;
    if (two) {                       // XCD partition: bid%8 -> XCD (heuristic)
        const int bid = blockIdx.x;
        const int xcd = bid & 7;
        gi  = xcd >> 2;              // XCD 0-3: graph 0, XCD 4-7: graph 1
        idx = (bid >> 3) * 4 + (xcd & 3);
    } else { gi = 0; idx = blockIdx.x; }
    if (idx >= 2 * NB) return;
    const int b    = idx >> 1;       // bucket
    const int half = idx & 1;        // 64-node half of the bucket
    const G g = gi ? g1 : g0;

    __shared__ int lcnt[HTILE];
    __shared__ unsigned short lrec[HTILE][CAPN];   // 12 KB, rows 16B-aligned
    for (int i = threadIdx.x; i < HTILE; i += 256) lcnt[i] = 0;
    __syncthreads();

    const int cnt  = min(g.bcnt[b], CAP);
    const int hsel = half << 6;
    const unsigned int* __restrict__ bp = g.bin + (size_t)b * CAP;
    for (int i = threadIdx.x; i < cnt; i += 256) {
        const unsigned int rec = bp[i];
        const int d = rec & (TILE - 1);
        if ((d & 64) == hsel) {
            const int p = atomicAdd(&lcnt[d & 63], 1);
            if (p < CAPN) lrec[d & 63][p] = (unsigned short)(rec >> TSH);
        }
    }
    __syncthreads();
    for (int t = threadIdx.x; t < HTILE; t += 256) {  // pad to x8 w/ sentinel
        const int c  = min(lcnt[t], CAPN);
        const int cp = (c + 7) & ~7;
        for (int p = c; p < cp; ++p) lrec[t][p] = (unsigned short)N;
        lcnt[t] = cp;
    }
    __syncthreads();

    const int grp = threadIdx.x >> 4;        // 16 groups of 16 lanes
    const int sub = threadIdx.x & 15;
    const uint2* __restrict__ vk2 = (const uint2*)g.vk;

    #pragma unroll
    for (int i = 0; i < 4; ++i) {
        const int nl = grp + 16 * i;
        const int n  = b * TILE + half * HTILE + nl;
        if (n >= N) continue;
        const int cp = lcnt[nl];

        unsigned int m0 = 0xFC00FC00u, m1 = 0xFC00FC00u;   // -inf halves
        for (int j = 0; j < cp; j += 8) {
            const uint4 rq = *(const uint4*)(&lrec[nl][j]);  // 8 recs, bcast
            unsigned int s[8];
            s[0] = rq.x & 0xFFFFu; s[1] = rq.x >> 16;
            s[2] = rq.y & 0xFFFFu; s[3] = rq.y >> 16;
            s[4] = rq.z & 0xFFFFu; s[5] = rq.z >> 16;
            s[6] = rq.w & 0xFFFFu; s[7] = rq.w >> 16;
            uint2 a[8];
            #pragma unroll
            for (int k = 0; k < 8; ++k) a[k] = vk2[(size_t)s[k] * 16 + sub];
            #pragma unroll
            for (int k = 0; k < 8; ++k) {
                m0 = pkmax(m0, a[k].x);
                m1 = pkmax(m1, a[k].y);
            }
        }

        float mv[4];
        mv[0] = h2f(m0 & 0xFFFFu); mv[1] = h2f(m0 >> 16);
        mv[2] = h2f(m1 & 0xFFFFu); mv[3] = h2f(m1 >> 16);

        const bool has = cp > 0;
        const float* __restrict__ urow = g.u + (size_t)n * HID;
        float* __restrict__ orow = g.out + (size_t)n * HID;
        #pragma unroll
        for (int t = 0; t < 4; ++t)
            orow[sub + 16 * t] =
                has ? fmaxf(urow[sub + 16 * t] + mv[t], 0.f) : 0.f;
    }
}

// ---------------- orchestration ----------------

extern "C" void kernel_launch(void* const* d_in, const int* in_sizes, int n_in,
                              void* d_out, int out_size, void* d_ws, size_t ws_size,
                              hipStream_t stream) {
    const float* x1  = (const float*)d_in[0];
    const int*   ei1 = (const int*)d_in[1];   // [2,E]: src row then dst row
    const float* x2  = (const float*)d_in[2];
    const int*   ei2 = (const int*)d_in[3];
    const float* W1  = (const float*)d_in[4];
    const float* b1  = (const float*)d_in[5];
    // d_in[6] = prelu_a: unused (identity on >=0)
    const float* W2  = (const float*)d_in[7];
    const float* b2  = (const float*)d_in[8];

    const int N  = in_sizes[0] / 32;
    const int E  = in_sizes[1] / 2;
    const int NB = (N + TILE - 1) / TILE;     // 391 for N=50000
    float* out = (float*)d_out;

    const size_t rowB = (size_t)N * HID * sizeof(float);            // 12.8 MB
    const size_t vkB  = ((size_t)(N + 1) * HID * 2 + 63) & ~(size_t)63;
    const size_t binB = ((size_t)NB * CAP * sizeof(int) + 63) & ~(size_t)63;
    const size_t nbB  = ((size_t)(NB + 2) * sizeof(int) + 63) & ~(size_t)63;
    const size_t wc1B = ((size_t)32 * 128 * 2 + 63) & ~(size_t)63;
    const size_t wc2B = ((size_t)64 * 128 * 2 + 63) & ~(size_t)63;

    const int bBlk = (E + 256 * EPT - 1) / (256 * EPT);   // 782 per graph
    const int gBlk = 512;
    const int pBlk = (32 * 64 + 64 * 64 + 2 * HID + 255) / 256;
    const int aggBlk2 = ((2 * NB + 3) / 4) * 8;   // XCD-partitioned 1D grid
    const int aggBlk1 = 2 * NB;

    _Float16* wc1 = nullptr;
    _Float16* wc2 = nullptr;

    auto run = [&](G ga, G gb, int ny) {
        // bcnt arrays contiguous across graphs: one memset when ny==2
        hipMemsetAsync(ga.bcnt, 0, (size_t)ny * nbB, stream);
        bin_kernel <<<dim3(bBlk, ny), 256, 0, stream>>>(ga, gb, E, NB);
        gemm_mfma_kernel<32><<<dim3(gBlk, ny), 256, 0, stream>>>(ga, gb, wc1, b1, N);
        if (ny == 2) agg_kernel<<<aggBlk2, 256, 0, stream>>>(ga, gb, N, NB, 1);
        else         agg_kernel<<<aggBlk1, 256, 0, stream>>>(ga, ga, N, NB, 0);
        gemm_mfma_kernel<64><<<dim3(gBlk, ny), 256, 0, stream>>>(ga, gb, wc2, b2, N);
        if (ny == 2) agg_kernel<<<aggBlk2, 256, 0, stream>>>(ga, gb, N, NB, 1);
        else         agg_kernel<<<aggBlk1, 256, 0, stream>>>(ga, ga, N, NB, 0);
    };

    char* ws = (char*)d_ws;
    const size_t needBoth = 2 * rowB + 2 * vkB + 2 * binB + 2 * nbB + wc1B + wc2B;

    if (ws_size >= needBoth) {
        float* u0 = (float*)ws;                  ws += rowB;
        float* u1 = (float*)ws;                  ws += rowB;
        unsigned int* bin0 = (unsigned int*)ws;  ws += binB;
        unsigned int* bin1 = (unsigned int*)ws;  ws += binB;
        unsigned short* vk0 = (unsigned short*)ws;  ws += vkB;
        unsigned short* vk1 = (unsigned short*)ws;  ws += vkB;
        wc1 = (_Float16*)ws;                     ws += wc1B;
        wc2 = (_Float16*)ws;                     ws += wc2B;
        int* bcnt0 = (int*)ws;                   ws += nbB;
        int* bcnt1 = (int*)ws;                   // contiguous with bcnt0

        G g0{x1, ei1, ei1 + E, bcnt0, bin0, u0, vk0, out};
        G g1{x2, ei2, ei2 + E, bcnt1, bin1, u1, vk1, out + (size_t)N * HID};
        prep_w_kernel<<<pBlk, 256, 0, stream>>>(W1, W2, wc1, wc2, vk0, vk1, N);
        run(g0, g1, 2);
    } else {
        // sequential fallback (~28 MB): one graph's buffers, reused
        float* u = (float*)ws;                   ws += rowB;
        unsigned int* bin = (unsigned int*)ws;   ws += binB;
        unsigned short* vk = (unsigned short*)ws;  ws += vkB;
        wc1 = (_Float16*)ws;                     ws += wc1B;
        wc2 = (_Float16*)ws;                     ws += wc2B;
        int* bcnt = (int*)ws;

        prep_w_kernel<<<pBlk, 256, 0, stream>>>(W1, W2, wc1, wc2, vk, vk, N);
        for (int g = 0; g < 2; ++g) {
            const int* ei = g ? ei2 : ei1;
            G gp{g ? x2 : x1, ei, ei + E, bcnt, bin,
                 u, vk, out + (size_t)g * N * HID};
            run(gp, gp, 1);
        }
    }
}